// Round 3
// baseline (353.913 us; speedup 1.0000x reference)
//
#include <hip/hip_runtime.h>
#include <hip/hip_bf16.h>

// MaskMLP R7: R6 + scalarized weight-pipeline registers (rule #20 fix).
// R6 post-mortem: f3[p][j]/f4[p][j] with p = r&1 are runtime-indexed at SROA
// time -> allocas -> 58MB scratch writes + 30MB scratch re-reads (WRITE_SIZE
// 57.9MB vs 0.5MB legit; VGPR stuck at 84). R7 replaces the rotating arrays
// with NAMED registers (A-slot = even rounds, B-slot = odd rounds) and
// hand-paired round macros with literal indices, so every access is a
// compile-time register reference. Wait schedule / LDS layout / math are
// identical to R6:
//   - W1..W4 global->VGPR, dist-2, per-round s_waitcnt vmcnt(2) fences
//   - activations h0..h3 in 48KB LDS, XOR-swizzled => 3 blocks/CU
//   - 5 barriers per block (h0/h1/h2/h3/reduce)
// gemm_l0 / cvt_all unchanged.

using bf16 = __hip_bfloat16;
typedef short bf16x8 __attribute__((ext_vector_type(8)));   // 8 bf16 = 4 VGPRs
typedef float f32x4 __attribute__((ext_vector_type(4)));

constexpr int B_ = 1024;   // batch
constexpr int M_ = 128;    // modules

#define WAITV(N) asm volatile("s_waitcnt vmcnt(" #N ")" ::: "memory")
#define WAITL()  asm volatile("s_waitcnt lgkmcnt(0)" ::: "memory")
#define BAR()    asm volatile("s_barrier" ::: "memory")
#define CFENCE() asm volatile("" ::: "memory")   // compiler-only ordering wall

#define MFMA(d, a, b) \
    d = __builtin_amdgcn_mfma_f32_16x16x32_bf16(a, b, d, 0, 0, 0)

// async global->LDS, 16B/lane; LDS dest = wave-uniform base + lane*16.
__device__ __forceinline__ void gload16_lds(const bf16* gp, bf16* lp) {
    __builtin_amdgcn_global_load_lds(
        (__attribute__((address_space(1))) void*)const_cast<bf16*>(gp),
        (__attribute__((address_space(3))) void*)lp,
        16, 0, 0);
}

// ---------------- fused fp32 -> bf16 conversion (x, W0..W4) ----------------
struct CvtArgs {
    const float4* src[6];
    short4* dst[6];
};
__global__ void cvt_all(CvtArgs a) {
    constexpr int starts[7] = {0, 1048576, 5242880, 5308416, 5570560,
                               6619136, 10813440};
    int i = blockIdx.x * blockDim.x + threadIdx.x;
    if (i >= starts[6]) return;
    int s = 0;
#pragma unroll
    for (int k = 1; k < 6; ++k) s += (i >= starts[k]) ? 1 : 0;
    int off = i - starts[s];
    float4 v = a.src[s][off];
    union { bf16 h[4]; short4 s4; } u;
    u.h[0] = __float2bfloat16(v.x);
    u.h[1] = __float2bfloat16(v.y);
    u.h[2] = __float2bfloat16(v.z);
    u.h[3] = __float2bfloat16(v.w);
    a.dst[s][off] = u.s4;
}

// ---------------- L0: h0 = relu(x @ W0^T + b0), K=4096 ----------------
__global__ __launch_bounds__(256, 2)
void gemm_l0(const bf16* __restrict__ A, const bf16* __restrict__ W,
             const float* __restrict__ bias, bf16* __restrict__ C) {
    constexpr int LDA = 4096;
    __shared__ __align__(16) bf16 sA[2][2][128 * 32];   // [set][half][row*32]
    __shared__ __align__(16) bf16 sB[2][2][64 * 32];

    const int tid = threadIdx.x, w = tid >> 6, lane = tid & 63;
    const int q = lane >> 4, ln = lane & 15;
    const int lr = lane >> 2, lk = lane & 3;
    const int swz = (lk ^ (lr & 3)) * 8;
    const int wm = w >> 1, wn = w & 1;
    const int r0 = blockIdx.y * 128, c0 = blockIdx.x * 64;

    auto stage = [&](int s, int set) {   // 6 gloads/wave
        const int k0 = s * 64;
#pragma unroll
        for (int h = 0; h < 2; ++h) {
#pragma unroll
            for (int t = 0; t < 2; ++t) {
                int grp = w * 2 + t;
                gload16_lds(A + (size_t)(r0 + grp * 16 + lr) * LDA + k0 + h * 32 + swz,
                            &sA[set][h][grp * 512]);
            }
            gload16_lds(W + (size_t)(c0 + w * 16 + lr) * LDA + k0 + h * 32 + swz,
                        &sB[set][h][w * 512]);
        }
    };

    f32x4 acc[4][2];
#pragma unroll
    for (int i = 0; i < 4; ++i)
#pragma unroll
        for (int j = 0; j < 2; ++j) acc[i][j] = (f32x4){0.f, 0.f, 0.f, 0.f};

    stage(0, 0);
    stage(1, 1);
    for (int r = 0; r < 64; ++r) {
        if (r < 63) WAITV(6); else WAITV(0);   // current stage arrived
        BAR();
        const int set = r & 1;
        bf16x8 aF[2][4], bF[2][2];
#pragma unroll
        for (int h = 0; h < 2; ++h) {
#pragma unroll
            for (int i = 0; i < 4; ++i) {
                int row = wm * 64 + i * 16 + ln;
                aF[h][i] = *(const bf16x8*)&sA[set][h][row * 32 + ((q ^ (row & 3)) * 8)];
            }
#pragma unroll
            for (int j = 0; j < 2; ++j) {
                int rn = wn * 32 + j * 16 + ln;
                bF[h][j] = *(const bf16x8*)&sB[set][h][rn * 32 + ((q ^ (rn & 3)) * 8)];
            }
        }
        WAITL();
        BAR();                                  // release this set
        if (r + 2 < 64) stage(r + 2, set);      // refill just-freed set
#pragma unroll
        for (int h = 0; h < 2; ++h)
#pragma unroll
            for (int i = 0; i < 4; ++i)
#pragma unroll
                for (int j = 0; j < 2; ++j)
                    acc[i][j] = __builtin_amdgcn_mfma_f32_16x16x32_bf16(
                        aF[h][i], bF[h][j], acc[i][j], 0, 0, 0);
    }

#pragma unroll
    for (int j = 0; j < 2; ++j) {
        int col = c0 + wn * 32 + j * 16 + ln;
        float bv = bias[col];
#pragma unroll
        for (int i = 0; i < 4; ++i)
#pragma unroll
            for (int rr = 0; rr < 4; ++rr) {
                int row = r0 + wm * 64 + i * 16 + q * 4 + rr;
                float v = acc[i][j][rr] + bv;
                v = v > 0.f ? v : 0.f;
                C[(size_t)row * 4096 + col] = __float2bfloat16(v);
            }
    }
}

// ---------------- fused L1..L4 + Wout + sigmoid ----------------
// grid (16 strips, 128 modules), 4 waves, 3 blocks/CU (48KB LDS).
// LDS pool (bf16 elems) -- ACTIVATIONS ONLY:
//   h3 [0,16384)     xor32  (P3->P4), overlays h1/h0 (dead by P3 epilogue)
//   h1 [0,4096)      xor8   (P1->P2)
//   h0 [4096,6144)   xor-col (gload_lds pre-swizzled, ->P1)
//   h2 [16384,24576) xor16  (P2->P3); float scratch reuses this after P4
__global__ __launch_bounds__(256, 3)
void modules_fused(const bf16* __restrict__ h0g,
                   const bf16* __restrict__ W1b, const float* __restrict__ b1,
                   const bf16* __restrict__ W2b, const float* __restrict__ b2,
                   const bf16* __restrict__ W3b, const float* __restrict__ b3,
                   const bf16* __restrict__ W4b, const float* __restrict__ b4,
                   const float* __restrict__ Wout, const float* __restrict__ bout,
                   float* __restrict__ out) {
    constexpr int H3 = 0, H1 = 0, H0 = 4096, H2 = 16384;
    __shared__ __align__(16) bf16 pool[24576];

    const int tid = threadIdx.x, w = tid >> 6, lane = tid & 63;
    const int q = lane >> 4, ln = lane & 15;
    const int lr = lane >> 2, lk = lane & 3;
    const int swz = (lk ^ (lr & 3)) * 8;
    const int m = blockIdx.y;
    const int r0 = blockIdx.x * 64;

    const bf16* W1m = W1b + (size_t)m * 64 * 32;
    const bf16* W2m = W2b + (size_t)m * 128 * 64;
    const bf16* W3m = W3b + (size_t)m * 256 * 128;
    const bf16* W4m = W4b + (size_t)m * 512 * 256;

    auto rdX = [&](int base, int nch, int row, int chunk) -> bf16x8 {
        return *(const bf16x8*)&pool[base + row * nch * 8 + ((chunk ^ (row & 7)) * 8)];
    };
    auto rdA0 = [&](int row) -> bf16x8 {   // h0: gload pre-swizzle layout
        return *(const bf16x8*)&pool[H0 + row * 32 + ((q ^ (row & 3)) * 8)];
    };
    auto wrX = [&](int base, int nch, int row, int col, float v) {
        pool[base + row * nch * 8 + (((col >> 3) ^ (row & 7)) * 8) + (col & 7)] =
            __float2bfloat16(v);
    };
    auto ldW = [&](const bf16* Wm, int ldg, int row, int kc) -> bf16x8 {
        return *(const bf16x8*)&Wm[(size_t)row * ldg + kc * 8];
    };

    // ---- epilogue scalars (drained by the WAITV(0) below)
    float b1v = b1[m * 64 + w * 16 + ln];
    float b2v[2], b3v[2][2], b4v[4][2], wov[4][2];
#pragma unroll
    for (int j = 0; j < 2; ++j) b2v[j] = b2[m * 128 + w * 32 + j * 16 + ln];
#pragma unroll
    for (int oc = 0; oc < 2; ++oc)
#pragma unroll
        for (int j = 0; j < 2; ++j)
            b3v[oc][j] = b3[m * 256 + oc * 128 + w * 32 + j * 16 + ln];
#pragma unroll
    for (int nc = 0; nc < 4; ++nc)
#pragma unroll
        for (int j = 0; j < 2; ++j) {
            int col = nc * 128 + w * 32 + j * 16 + ln;
            b4v[nc][j] = b4[(size_t)m * 512 + col];
            wov[nc][j] = Wout[(size_t)m * 512 + col];
        }
    float boutv = bout[m];

    // ---- h0 strip -> LDS; W1/W2 + W3 rounds 0,1 -> NAMED regs
    gload16_lds(h0g + (size_t)(r0 + w * 16 + lr) * 4096 + m * 32 + swz,
                pool + H0 + w * 512);
    bf16x8 f1   = ldW(W1m, 32, w * 16 + ln, q);
    bf16x8 f2A0 = ldW(W2m, 64, w * 32 + ln,      q);
    bf16x8 f2A1 = ldW(W2m, 64, w * 32 + 16 + ln, q);
    bf16x8 f2B0 = ldW(W2m, 64, w * 32 + ln,      4 + q);
    bf16x8 f2B1 = ldW(W2m, 64, w * 32 + 16 + ln, 4 + q);
    bf16x8 f3A0 = ldW(W3m, 128, w * 32 + ln,      q);
    bf16x8 f3A1 = ldW(W3m, 128, w * 32 + 16 + ln, q);
    bf16x8 f3B0 = ldW(W3m, 128, w * 32 + ln,      4 + q);
    bf16x8 f3B1 = ldW(W3m, 128, w * 32 + 16 + ln, 4 + q);
    WAITV(0);
    BAR();   // h0 visible to all waves

    // ================= P1: h1 = relu(h0 @ W1^T + b1) =================
    {
        f32x4 a1[4];
#pragma unroll
        for (int i = 0; i < 4; ++i) {
            a1[i] = (f32x4){0.f, 0.f, 0.f, 0.f};
            MFMA(a1[i], rdA0(i * 16 + ln), f1);
        }
        int col = w * 16 + ln;
#pragma unroll
        for (int i = 0; i < 4; ++i)
#pragma unroll
            for (int rr = 0; rr < 4; ++rr) {
                float v = a1[i][rr] + b1v;
                wrX(H1, 8, i * 16 + q * 4 + rr, col, v > 0.f ? v : 0.f);
            }
        WAITL();
        BAR();   // h1 visible
    }

    // ================= P2: h2 = relu(h1 @ W2^T + b2) =================
    {
        f32x4 a2[4][2];
#pragma unroll
        for (int i = 0; i < 4; ++i)
#pragma unroll
            for (int j = 0; j < 2; ++j) a2[i][j] = (f32x4){0.f, 0.f, 0.f, 0.f};
        {   // kk = 0 (slot A)
            bf16x8 x0 = rdX(H1, 8,  0 + ln, q);
            bf16x8 x1 = rdX(H1, 8, 16 + ln, q);
            bf16x8 x2 = rdX(H1, 8, 32 + ln, q);
            bf16x8 x3 = rdX(H1, 8, 48 + ln, q);
            MFMA(a2[0][0], x0, f2A0); MFMA(a2[0][1], x0, f2A1);
            MFMA(a2[1][0], x1, f2A0); MFMA(a2[1][1], x1, f2A1);
            MFMA(a2[2][0], x2, f2A0); MFMA(a2[2][1], x2, f2A1);
            MFMA(a2[3][0], x3, f2A0); MFMA(a2[3][1], x3, f2A1);
        }
        {   // kk = 1 (slot B)
            bf16x8 x0 = rdX(H1, 8,  0 + ln, 4 + q);
            bf16x8 x1 = rdX(H1, 8, 16 + ln, 4 + q);
            bf16x8 x2 = rdX(H1, 8, 32 + ln, 4 + q);
            bf16x8 x3 = rdX(H1, 8, 48 + ln, 4 + q);
            MFMA(a2[0][0], x0, f2B0); MFMA(a2[0][1], x0, f2B1);
            MFMA(a2[1][0], x1, f2B0); MFMA(a2[1][1], x1, f2B1);
            MFMA(a2[2][0], x2, f2B0); MFMA(a2[2][1], x2, f2B1);
            MFMA(a2[3][0], x3, f2B0); MFMA(a2[3][1], x3, f2B1);
        }
#pragma unroll
        for (int j = 0; j < 2; ++j)
#pragma unroll
            for (int i = 0; i < 4; ++i)
#pragma unroll
                for (int rr = 0; rr < 4; ++rr) {
                    float v = a2[i][j][rr] + b2v[j];
                    wrX(H2, 16, i * 16 + q * 4 + rr, w * 32 + j * 16 + ln,
                        v > 0.f ? v : 0.f);
                }
        WAITL();
        BAR();   // h2 visible
    }

    // ===== P3: h3 = relu(h2 @ W3^T + b3); dist-2 reg-stream, NAMED slots =====
    // Round R consumes slot (R&1 ? B : A) and prefetches R+2 into the SAME
    // slot. Rounds 0,1 use prologue-drained primes (CFENCE only); steady
    // rounds enter with pairs (R),(R+1) in flight -> WAITV(2); round 7 drains.
#define P3R(R, F0, F1)                                                        \
    {                                                                         \
        bf16x8 c0 = F0, c1 = F1;                                              \
        if ((R) + 2 < 8) {                                                    \
            F0 = ldW(W3m, 128, (((R) + 2) >> 2) * 128 + w * 32 + ln,          \
                     (((R) + 2) & 3) * 4 + q);                                \
            F1 = ldW(W3m, 128, (((R) + 2) >> 2) * 128 + w * 32 + 16 + ln,     \
                     (((R) + 2) & 3) * 4 + q);                                \
        }                                                                     \
        bf16x8 x0 = rdX(H2, 16,  0 + ln, ((R) & 3) * 4 + q);                  \
        bf16x8 x1 = rdX(H2, 16, 16 + ln, ((R) & 3) * 4 + q);                  \
        bf16x8 x2 = rdX(H2, 16, 32 + ln, ((R) & 3) * 4 + q);                  \
        bf16x8 x3 = rdX(H2, 16, 48 + ln, ((R) & 3) * 4 + q);                  \
        MFMA(a3[0][0], x0, c0); MFMA(a3[0][1], x0, c1);                       \
        MFMA(a3[1][0], x1, c0); MFMA(a3[1][1], x1, c1);                       \
        MFMA(a3[2][0], x2, c0); MFMA(a3[2][1], x2, c1);                       \
        MFMA(a3[3][0], x3, c0); MFMA(a3[3][1], x3, c1);                       \
    }
#define P3EPI(OC)                                                             \
    _Pragma("unroll") for (int j = 0; j < 2; ++j)                             \
        _Pragma("unroll") for (int i = 0; i < 4; ++i)                         \
            _Pragma("unroll") for (int rr = 0; rr < 4; ++rr) {                \
                float v = a3[i][j][rr] + b3v[OC][j];                          \
                wrX(H3, 32, i * 16 + q * 4 + rr,                              \
                    (OC) * 128 + w * 32 + j * 16 + ln, v > 0.f ? v : 0.f);    \
            }
    {
        f32x4 a3[4][2];
#pragma unroll
        for (int i = 0; i < 4; ++i)
#pragma unroll
            for (int j = 0; j < 2; ++j) a3[i][j] = (f32x4){0.f, 0.f, 0.f, 0.f};
        CFENCE(); P3R(0, f3A0, f3A1);
        CFENCE(); P3R(1, f3B0, f3B1);
        WAITV(2); P3R(2, f3A0, f3A1);
        WAITV(2); P3R(3, f3B0, f3B1);
        P3EPI(0);
#pragma unroll
        for (int i = 0; i < 4; ++i)
#pragma unroll
            for (int j = 0; j < 2; ++j) a3[i][j] = (f32x4){0.f, 0.f, 0.f, 0.f};
        WAITV(2); P3R(4, f3A0, f3A1);
        WAITV(2); P3R(5, f3B0, f3B1);
        WAITV(2); P3R(6, f3A0, f3A1);
        WAITV(0); P3R(7, f3B0, f3B1);
        P3EPI(1);
    }
    // prime W4 rounds 0,1 (VGPR dest: safe to stay in flight across the bar)
    bf16x8 f4A0 = ldW(W4m, 256, w * 32 + ln,      q);
    bf16x8 f4A1 = ldW(W4m, 256, w * 32 + 16 + ln, q);
    bf16x8 f4B0 = ldW(W4m, 256, w * 32 + ln,      4 + q);
    bf16x8 f4B1 = ldW(W4m, 256, w * 32 + 16 + ln, 4 + q);
    WAITL();
    BAR();   // h3 visible; h2 dead for all waves

    // == P4: L4 (4 nc-chunks of 128 cols) + Wout dot; dist-2, NAMED slots ==
    float pl[4][4];
#pragma unroll
    for (int i = 0; i < 4; ++i)
#pragma unroll
        for (int rr = 0; rr < 4; ++rr) pl[i][rr] = 0.f;

#define P4R(NC, KR, F0, F1)                                                   \
    {                                                                         \
        bf16x8 c0 = F0, c1 = F1;                                              \
        if ((NC) * 8 + (KR) + 2 < 32) {                                       \
            constexpr int r2_ = (NC) * 8 + (KR) + 2;                          \
            F0 = ldW(W4m, 256, (r2_ >> 3) * 128 + w * 32 + ln,                \
                     (r2_ & 7) * 4 + q);                                      \
            F1 = ldW(W4m, 256, (r2_ >> 3) * 128 + w * 32 + 16 + ln,           \
                     (r2_ & 7) * 4 + q);                                      \
        }                                                                     \
        bf16x8 x0 = rdX(H3, 32,  0 + ln, (KR) * 4 + q);                       \
        bf16x8 x1 = rdX(H3, 32, 16 + ln, (KR) * 4 + q);                       \
        bf16x8 x2 = rdX(H3, 32, 32 + ln, (KR) * 4 + q);                       \
        bf16x8 x3 = rdX(H3, 32, 48 + ln, (KR) * 4 + q);                       \
        MFMA(a4[0][0], x0, c0); MFMA(a4[0][1], x0, c1);                       \
        MFMA(a4[1][0], x1, c0); MFMA(a4[1][1], x1, c1);                       \
        MFMA(a4[2][0], x2, c0); MFMA(a4[2][1], x2, c1);                       \
        MFMA(a4[3][0], x3, c0); MFMA(a4[3][1], x3, c1);                       \
    }
#define P4NC(NC, LASTWAIT)                                                    \
    {                                                                         \
        f32x4 a4[4][2];                                                       \
        _Pragma("unroll") for (int i = 0; i < 4; ++i)                         \
            _Pragma("unroll") for (int j = 0; j < 2; ++j)                     \
                a4[i][j] = (f32x4){0.f, 0.f, 0.f, 0.f};                       \
        WAITV(2); P4R(NC, 0, f4A0, f4A1);                                     \
        WAITV(2); P4R(NC, 1, f4B0, f4B1);                                     \
        WAITV(2); P4R(NC, 2, f4A0, f4A1);                                     \
        WAITV(2); P4R(NC, 3, f4B0, f4B1);                                     \
        WAITV(2); P4R(NC, 4, f4A0, f4A1);                                     \
        WAITV(2); P4R(NC, 5, f4B0, f4B1);                                     \
        WAITV(2); P4R(NC, 6, f4A0, f4A1);                                     \
        LASTWAIT; P4R(NC, 7, f4B0, f4B1);                                     \
        _Pragma("unroll") for (int j = 0; j < 2; ++j) {                       \
            float bb = b4v[NC][j], wv = wov[NC][j];                           \
            _Pragma("unroll") for (int i = 0; i < 4; ++i)                     \
                _Pragma("unroll") for (int rr = 0; rr < 4; ++rr) {            \
                    float v = a4[i][j][rr] + bb;                              \
                    v = v > 0.f ? v : 0.f;                                    \
                    pl[i][rr] += v * wv;                                      \
                }                                                             \
        }                                                                     \
    }
    P4NC(0, WAITV(2));
    P4NC(1, WAITV(2));
    P4NC(2, WAITV(2));
    P4NC(3, WAITV(0));

    // ---- reduce: 16 col-lanes via shuffle, 4 waves via LDS, sigmoid store ----
    // scratch over dead h2 [16384..): lagging waves only read h3 [0,16384).
    float* sc = (float*)&pool[H2];
#pragma unroll
    for (int i = 0; i < 4; ++i)
#pragma unroll
        for (int rr = 0; rr < 4; ++rr) {
            float p = pl[i][rr];
            p += __shfl_xor(p, 1);
            p += __shfl_xor(p, 2);
            p += __shfl_xor(p, 4);
            p += __shfl_xor(p, 8);
            if (ln == 0) sc[w * 64 + i * 16 + q * 4 + rr] = p;
        }
    __syncthreads();   // vmcnt already 0 here; safe
    if (tid < 64) {
        float s = sc[tid] + sc[64 + tid] + sc[128 + tid] + sc[192 + tid];
        float lg = s + boutv;
        out[(size_t)(r0 + tid) * M_ + m] = 1.f / (1.f + __expf(-lg));
    }
}

// ---------------- host ----------------
extern "C" void kernel_launch(void* const* d_in, const int* in_sizes, int n_in,
                              void* d_out, int out_size, void* d_ws, size_t ws_size,
                              hipStream_t stream) {
    const float* x    = (const float*)d_in[0];
    const float* W0   = (const float*)d_in[1];
    const float* b0   = (const float*)d_in[2];
    const float* W1   = (const float*)d_in[3];
    const float* b1   = (const float*)d_in[4];
    const float* W2   = (const float*)d_in[5];
    const float* b2   = (const float*)d_in[6];
    const float* W3   = (const float*)d_in[7];
    const float* b3   = (const float*)d_in[8];
    const float* W4   = (const float*)d_in[9];
    const float* b4   = (const float*)d_in[10];
    const float* Wout = (const float*)d_in[11];
    const float* bout = (const float*)d_in[12];
    float* out = (float*)d_out;

    char* ws = (char*)d_ws;
    size_t off = 0;
    auto alloc = [&](size_t bytes) -> void* {
        off = (off + 255) & ~(size_t)255;
        void* p = ws + off;
        off += bytes;
        return p;
    };
    bf16* W0b = (bf16*)alloc((size_t)4096 * 4096 * 2);
    bf16* W1b = (bf16*)alloc((size_t)M_ * 64 * 32 * 2);
    bf16* W2b = (bf16*)alloc((size_t)M_ * 128 * 64 * 2);
    bf16* W3b = (bf16*)alloc((size_t)M_ * 256 * 128 * 2);
    bf16* W4b = (bf16*)alloc((size_t)M_ * 512 * 256 * 2);
    bf16* xb  = (bf16*)alloc((size_t)B_ * 4096 * 2);
    bf16* h0  = (bf16*)alloc((size_t)B_ * 4096 * 2);   // [B][128][32]

    CvtArgs ca;
    ca.src[0] = (const float4*)x;  ca.dst[0] = (short4*)xb;
    ca.src[1] = (const float4*)W0; ca.dst[1] = (short4*)W0b;
    ca.src[2] = (const float4*)W1; ca.dst[2] = (short4*)W1b;
    ca.src[3] = (const float4*)W2; ca.dst[3] = (short4*)W2b;
    ca.src[4] = (const float4*)W3; ca.dst[4] = (short4*)W3b;
    ca.src[5] = (const float4*)W4; ca.dst[5] = (short4*)W4b;
    cvt_all<<<(10813440 + 255) / 256, 256, 0, stream>>>(ca);

    {
        dim3 g(4096 / 64, B_ / 128, 1);
        gemm_l0<<<g, 256, 0, stream>>>(xb, W0b, b0, h0);
    }
    {
        dim3 g(B_ / 64, M_, 1);
        modules_fused<<<g, 256, 0, stream>>>(h0, W1b, b1, W2b, b2, W3b, b3,
                                             W4b, b4, Wout, bout, out);
    }
}

// Round 5
// 328.857 us; speedup vs baseline: 1.0762x; 1.0762x over previous
//
#include <hip/hip_runtime.h>
#include <hip/hip_bf16.h>

// MaskMLP R8 (resubmit; round-4 bench died to container infra, no verdict).
// R4's proven W-LDS-staging pipeline, compacted to 49KB LDS
// -> 3 blocks/CU (was 64KB -> 2 blocks/CU, Occupancy 20%).
// R5-R7 post-mortem: register-streamed weights produced a persistent
// unexplained scratch signature (VGPR pinned 84, WRITE_SIZE 58-307MB) and
// never beat R4's 83us. Reverted. This round changes ONLY the memory map:
//   - h3: padded stride 264 -> xor32 chunk layout (16896 -> 16384 elems)
//   - h1 overlaid into the W3-buffer region (dead before W3 s1 staging)
//   - h0/h2 share a base (h0 dead before h2's first write)
//   - P4: triple-buffer dist-2 -> double-buffer dist-1 (R4's P3 pattern)
// Pool layout (bf16 elems), temporal overlays:
//   [0,4096)      W2 s0 (P2)   -> W3 s0 part (P3) -> h3 (P4)
//   [4096,8192)   W2 s1 (P2)   -> W3 s0 part      -> h3
//   [8192,10240)  W1 (P1)      -> W3 s1 part      -> h3
//   [10240,14848) h1 (P1->P2)  -> W3 s1 part      -> h3
//   [14848,16384) W3 s1 part   -> h3
//   [16384,18432) h0 (->P1)    -> h2 (P2->P3) -> W4 b0 (P4)
//   [18432,20480)               h2            -> W4 b0
//   [20480,24576)               h2            -> W4 b1
//   [24576,25088)               h2 tail       -> reduce scratch
// gemm_l0 / cvt_all unchanged.

using bf16 = __hip_bfloat16;
typedef short bf16x8 __attribute__((ext_vector_type(8)));   // 8 bf16 = 4 VGPRs
typedef float f32x4 __attribute__((ext_vector_type(4)));

constexpr int B_ = 1024;   // batch
constexpr int M_ = 128;    // modules

#define WAITV(N) asm volatile("s_waitcnt vmcnt(" #N ")" ::: "memory")
#define WAITL()  asm volatile("s_waitcnt lgkmcnt(0)" ::: "memory")
#define BAR()    asm volatile("s_barrier" ::: "memory")

// async global->LDS, 16B/lane; LDS dest = wave-uniform base + lane*16.
__device__ __forceinline__ void gload16_lds(const bf16* gp, bf16* lp) {
    __builtin_amdgcn_global_load_lds(
        (__attribute__((address_space(1))) void*)const_cast<bf16*>(gp),
        (__attribute__((address_space(3))) void*)lp,
        16, 0, 0);
}

// ---------------- fused fp32 -> bf16 conversion (x, W0..W4) ----------------
struct CvtArgs {
    const float4* src[6];
    short4* dst[6];
};
__global__ void cvt_all(CvtArgs a) {
    constexpr int starts[7] = {0, 1048576, 5242880, 5308416, 5570560,
                               6619136, 10813440};
    int i = blockIdx.x * blockDim.x + threadIdx.x;
    if (i >= starts[6]) return;
    int s = 0;
#pragma unroll
    for (int k = 1; k < 6; ++k) s += (i >= starts[k]) ? 1 : 0;
    int off = i - starts[s];
    float4 v = a.src[s][off];
    union { bf16 h[4]; short4 s4; } u;
    u.h[0] = __float2bfloat16(v.x);
    u.h[1] = __float2bfloat16(v.y);
    u.h[2] = __float2bfloat16(v.z);
    u.h[3] = __float2bfloat16(v.w);
    a.dst[s][off] = u.s4;
}

// ---------------- L0: h0 = relu(x @ W0^T + b0), K=4096 ----------------
// 128x64 tile, BK=64 (two 32-k halves per stage), 2 LDS sets, prefetch dist 2.
__global__ __launch_bounds__(256, 2)
void gemm_l0(const bf16* __restrict__ A, const bf16* __restrict__ W,
             const float* __restrict__ bias, bf16* __restrict__ C) {
    constexpr int LDA = 4096;
    __shared__ __align__(16) bf16 sA[2][2][128 * 32];   // [set][half][row*32]
    __shared__ __align__(16) bf16 sB[2][2][64 * 32];

    const int tid = threadIdx.x, w = tid >> 6, lane = tid & 63;
    const int q = lane >> 4, ln = lane & 15;
    const int lr = lane >> 2, lk = lane & 3;
    const int swz = (lk ^ (lr & 3)) * 8;
    const int wm = w >> 1, wn = w & 1;
    const int r0 = blockIdx.y * 128, c0 = blockIdx.x * 64;

    auto stage = [&](int s, int set) {   // 6 gloads/wave
        const int k0 = s * 64;
#pragma unroll
        for (int h = 0; h < 2; ++h) {
#pragma unroll
            for (int t = 0; t < 2; ++t) {
                int grp = w * 2 + t;
                gload16_lds(A + (size_t)(r0 + grp * 16 + lr) * LDA + k0 + h * 32 + swz,
                            &sA[set][h][grp * 512]);
            }
            gload16_lds(W + (size_t)(c0 + w * 16 + lr) * LDA + k0 + h * 32 + swz,
                        &sB[set][h][w * 512]);
        }
    };

    f32x4 acc[4][2];
#pragma unroll
    for (int i = 0; i < 4; ++i)
#pragma unroll
        for (int j = 0; j < 2; ++j) acc[i][j] = (f32x4){0.f, 0.f, 0.f, 0.f};

    stage(0, 0);
    stage(1, 1);
    for (int r = 0; r < 64; ++r) {
        if (r < 63) WAITV(6); else WAITV(0);   // current stage arrived
        BAR();
        const int set = r & 1;
        bf16x8 aF[2][4], bF[2][2];
#pragma unroll
        for (int h = 0; h < 2; ++h) {
#pragma unroll
            for (int i = 0; i < 4; ++i) {
                int row = wm * 64 + i * 16 + ln;
                aF[h][i] = *(const bf16x8*)&sA[set][h][row * 32 + ((q ^ (row & 3)) * 8)];
            }
#pragma unroll
            for (int j = 0; j < 2; ++j) {
                int rn = wn * 32 + j * 16 + ln;
                bF[h][j] = *(const bf16x8*)&sB[set][h][rn * 32 + ((q ^ (rn & 3)) * 8)];
            }
        }
        WAITL();
        BAR();                                  // release this set
        if (r + 2 < 64) stage(r + 2, set);      // refill just-freed set
#pragma unroll
        for (int h = 0; h < 2; ++h)
#pragma unroll
            for (int i = 0; i < 4; ++i)
#pragma unroll
                for (int j = 0; j < 2; ++j)
                    acc[i][j] = __builtin_amdgcn_mfma_f32_16x16x32_bf16(
                        aF[h][i], bF[h][j], acc[i][j], 0, 0, 0);
    }

#pragma unroll
    for (int j = 0; j < 2; ++j) {
        int col = c0 + wn * 32 + j * 16 + ln;
        float bv = bias[col];
#pragma unroll
        for (int i = 0; i < 4; ++i)
#pragma unroll
            for (int rr = 0; rr < 4; ++rr) {
                int row = r0 + wm * 64 + i * 16 + q * 4 + rr;
                float v = acc[i][j][rr] + bv;
                v = v > 0.f ? v : 0.f;
                C[(size_t)row * 4096 + col] = __float2bfloat16(v);
            }
    }
}

// ---------------- fused L1..L4 + Wout + sigmoid ----------------
// grid (16 strips, 128 modules), 4 waves, 49KB LDS -> 3 blocks/CU.
__global__ __launch_bounds__(256, 2)
void modules_fused(const bf16* __restrict__ h0g,
                   const bf16* __restrict__ W1b, const float* __restrict__ b1,
                   const bf16* __restrict__ W2b, const float* __restrict__ b2,
                   const bf16* __restrict__ W3b, const float* __restrict__ b3,
                   const bf16* __restrict__ W4b, const float* __restrict__ b4,
                   const float* __restrict__ Wout, const float* __restrict__ bout,
                   float* __restrict__ out) {
    constexpr int H3O = 0;          // h3 xor32, [0,16384)
    constexpr int W1B = 8192;       // W1 buf (P1), 2048
    constexpr int H1O = 10240;      // h1 stride 72, [10240,14848)
    constexpr int H0O = 16384;      // h0, [16384,18432)
    constexpr int H2O = 16384;      // h2 stride 136, [16384,25088) (over dead h0)
    constexpr int P4B0 = 16384, P4B1 = 20480;   // W4 dbl bufs (over dead h2)
    constexpr int SCO = 24576;      // reduce scratch, [24576,25088)
    __shared__ __align__(16) bf16 pool[25088];

    const int tid = threadIdx.x, w = tid >> 6, lane = tid & 63;
    const int q = lane >> 4, ln = lane & 15;
    const int lr = lane >> 2, lk = lane & 3;
    const int swz = (lk ^ (lr & 3)) * 8;
    const int m = blockIdx.y;
    const int r0 = blockIdx.x * 64;

    const bf16* W1m = W1b + (size_t)m * 64 * 32;
    const bf16* W2m = W2b + (size_t)m * 128 * 64;
    const bf16* W3m = W3b + (size_t)m * 256 * 128;
    const bf16* W4m = W4b + (size_t)m * 512 * 256;

    auto stage = [&](const bf16* G, int ldg, int rows, int nr0, int k0, int woff) {
#pragma unroll
        for (int t = 0; t < rows / 64; ++t) {
            int r = t * 64 + w * 16 + lr;
            gload16_lds(G + (size_t)(nr0 + r) * ldg + k0 + swz,
                        pool + woff + t * 2048 + w * 512);
        }
    };
    auto rdA = [&](int hoff, int stride, int row, int kc) -> bf16x8 {
        return *(const bf16x8*)&pool[hoff + row * stride + kc * 8];
    };
    auto rdA0 = [&](int row) -> bf16x8 {   // h0, xor layout, kc = q
        return *(const bf16x8*)&pool[H0O + row * 32 + ((q ^ (row & 3)) * 8)];
    };
    auto rdB = [&](int woff, int rn) -> bf16x8 {
        return *(const bf16x8*)&pool[woff + rn * 32 + ((q ^ (rn & 3)) * 8)];
    };
    auto wrH = [&](int hoff, int stride, int row, int col, float v) {
        pool[hoff + row * stride + col] = __float2bfloat16(v);
    };
    // h3 xor32 layout: elem = row*256 + ((col>>3)^(row&7))*8 + (col&7)
    auto wrH3 = [&](int row, int col, float v) {
        pool[H3O + row * 256 + (((col >> 3) ^ (row & 7)) * 8) + (col & 7)] =
            __float2bfloat16(v);
    };
    auto rdA3 = [&](int row, int kc) -> bf16x8 {
        return *(const bf16x8*)&pool[H3O + row * 256 + ((kc ^ (row & 7)) * 8)];
    };

    // ---- preload all epilogue scalars, then drain vmcnt so counts are exact
    float b1v = b1[m * 64 + w * 16 + ln];
    float b2v[2], b3v[4], b4v[4][2], wov[4][2];
#pragma unroll
    for (int j = 0; j < 2; ++j) b2v[j] = b2[m * 128 + w * 32 + j * 16 + ln];
#pragma unroll
    for (int j = 0; j < 4; ++j) b3v[j] = b3[m * 256 + w * 64 + j * 16 + ln];
#pragma unroll
    for (int nc = 0; nc < 4; ++nc)
#pragma unroll
        for (int j = 0; j < 2; ++j) {
            int col = nc * 128 + w * 32 + j * 16 + ln;
            b4v[nc][j] = b4[(size_t)m * 512 + col];
            wov[nc][j] = Wout[(size_t)m * 512 + col];
        }
    float boutv = bout[m];
    WAITV(0);

    // ---- issue: h0 strip (1), W1 (1), P2 s0 (2), P2 s1 (2) -> out=6
    gload16_lds(h0g + (size_t)(r0 + w * 16 + lr) * 4096 + m * 32 + swz,
                pool + H0O + w * 512);
    stage(W1m, 32, 64, 0, 0, W1B);
    stage(W2m, 64, 128, 0, 0, 0);
    stage(W2m, 64, 128, 0, 32, 4096);

    // ================= P1: h1 = relu(h0 @ W1^T + b1) =================
    WAITV(4);   // h0 + W1 arrived; P2 stages remain in flight
    BAR();
    {
        bf16x8 aF[4], bF;
#pragma unroll
        for (int i = 0; i < 4; ++i) aF[i] = rdA0(i * 16 + ln);
        bF = rdB(W1B, w * 16 + ln);
        WAITL();
        BAR();
        f32x4 a1[4];
#pragma unroll
        for (int i = 0; i < 4; ++i) {
            a1[i] = (f32x4){0.f, 0.f, 0.f, 0.f};
            a1[i] = __builtin_amdgcn_mfma_f32_16x16x32_bf16(aF[i], bF, a1[i], 0, 0, 0);
        }
        int col = w * 16 + ln;
#pragma unroll
        for (int i = 0; i < 4; ++i)
#pragma unroll
            for (int rr = 0; rr < 4; ++rr) {
                float v = a1[i][rr] + b1v;
                v = v > 0.f ? v : 0.f;
                wrH(H1O, 72, i * 16 + q * 4 + rr, col, v);
            }
        WAITL();
        BAR();   // h1 visible
    }

    // ================= P2: h2 = relu(h1 @ W2^T + b2), 2 rounds =================
    {
        f32x4 a2[4][2];
#pragma unroll
        for (int i = 0; i < 4; ++i)
#pragma unroll
            for (int j = 0; j < 2; ++j) a2[i][j] = (f32x4){0.f, 0.f, 0.f, 0.f};
#pragma unroll
        for (int kr = 0; kr < 2; ++kr) {
            if (kr == 0) WAITV(2); else WAITV(0);
            BAR();
            bf16x8 aF[4], bF[2];
#pragma unroll
            for (int i = 0; i < 4; ++i) aF[i] = rdA(H1O, 72, i * 16 + ln, kr * 4 + q);
#pragma unroll
            for (int j = 0; j < 2; ++j) bF[j] = rdB(kr * 4096, w * 32 + j * 16 + ln);
            WAITL();
            BAR();
            if (kr == 1) {               // P3 s0,s1 (4+4) over consumed P2 bufs + dead W1/h1
                stage(W3m, 128, 256, 0, 0, 0);
                stage(W3m, 128, 256, 0, 32, 8192);
            }
#pragma unroll
            for (int i = 0; i < 4; ++i)
#pragma unroll
                for (int j = 0; j < 2; ++j)
                    a2[i][j] = __builtin_amdgcn_mfma_f32_16x16x32_bf16(aF[i], bF[j], a2[i][j], 0, 0, 0);
        }
#pragma unroll
        for (int j = 0; j < 2; ++j) {
            int col = w * 32 + j * 16 + ln;
#pragma unroll
            for (int i = 0; i < 4; ++i)
#pragma unroll
                for (int rr = 0; rr < 4; ++rr) {
                    float v = a2[i][j][rr] + b2v[j];
                    v = v > 0.f ? v : 0.f;
                    wrH(H2O, 136, i * 16 + q * 4 + rr, col, v);
                }
        }
        WAITL();
        BAR();   // h2 visible (over dead h0)
    }

    // ================= P3: h3 = relu(h2 @ W3^T + b3), 4 rounds, dist-1 =================
    {
        f32x4 a3[4][4];
#pragma unroll
        for (int i = 0; i < 4; ++i)
#pragma unroll
            for (int j = 0; j < 4; ++j) a3[i][j] = (f32x4){0.f, 0.f, 0.f, 0.f};
#pragma unroll
        for (int kr = 0; kr < 4; ++kr) {
            if (kr < 3) WAITV(4); else WAITV(0);
            BAR();
            bf16x8 aF[4], bF[4];
#pragma unroll
            for (int i = 0; i < 4; ++i) aF[i] = rdA(H2O, 136, i * 16 + ln, kr * 4 + q);
#pragma unroll
            for (int j = 0; j < 4; ++j) bF[j] = rdB((kr & 1) * 8192, w * 64 + j * 16 + ln);
            WAITL();
            BAR();
            if (kr == 0)      stage(W3m, 128, 256, 0, 64, 0);       // s2
            else if (kr == 1) stage(W3m, 128, 256, 0, 96, 8192);    // s3
            else if (kr == 3) {                                     // P4 s0,s1 (2+2)
                stage(W4m, 256, 128, 0, 0, P4B0);
                stage(W4m, 256, 128, 0, 32, P4B1);
            }
#pragma unroll
            for (int i = 0; i < 4; ++i)
#pragma unroll
                for (int j = 0; j < 4; ++j)
                    a3[i][j] = __builtin_amdgcn_mfma_f32_16x16x32_bf16(aF[i], bF[j], a3[i][j], 0, 0, 0);
        }
        // h3 (xor32) over dead W3 bufs: all bF reads drained at kr=3's WAITL+BAR
#pragma unroll
        for (int j = 0; j < 4; ++j) {
            int col = w * 64 + j * 16 + ln;
#pragma unroll
            for (int i = 0; i < 4; ++i)
#pragma unroll
                for (int rr = 0; rr < 4; ++rr) {
                    float v = a3[i][j][rr] + b3v[j];
                    v = v > 0.f ? v : 0.f;
                    wrH3(i * 16 + q * 4 + rr, col, v);
                }
        }
        WAITL();
        BAR();   // h3 visible
    }

    // == P4: L4 (512 cols in 4 nc-chunks of 128) + Wout dot; dbl-buf dist-1 ==
    // Round r reads buf[r&1], then (after WAITL+BAR) restages tile r+2 into
    // the same buf (R4's P3 pattern). Entry: s_r done, s_{r+1} in flight
    // -> WAITV(2); last round drains.
    float pl[4][4];
#pragma unroll
    for (int i = 0; i < 4; ++i)
#pragma unroll
        for (int rr = 0; rr < 4; ++rr) pl[i][rr] = 0.f;

#pragma unroll
    for (int nc = 0; nc < 4; ++nc) {
        f32x4 a4[4][2];
#pragma unroll
        for (int i = 0; i < 4; ++i)
#pragma unroll
            for (int j = 0; j < 2; ++j) a4[i][j] = (f32x4){0.f, 0.f, 0.f, 0.f};
#pragma unroll
        for (int kr = 0; kr < 8; ++kr) {
            const int r = nc * 8 + kr;
            if (r < 31) WAITV(2); else WAITV(0);
            BAR();
            const int wb = (r & 1) ? P4B1 : P4B0;
            bf16x8 aF[4], bF[2];
#pragma unroll
            for (int i = 0; i < 4; ++i) aF[i] = rdA3(i * 16 + ln, kr * 4 + q);
#pragma unroll
            for (int j = 0; j < 2; ++j) bF[j] = rdB(wb, w * 32 + j * 16 + ln);
            WAITL();
            BAR();
            if (r + 2 < 32) {   // restage just-read buffer with tile r+2
                const int r2 = r + 2;
                stage(W4m, 256, 128, (r2 >> 3) * 128, (r2 & 7) * 32, wb);
            }
#pragma unroll
            for (int i = 0; i < 4; ++i)
#pragma unroll
                for (int j = 0; j < 2; ++j)
                    a4[i][j] = __builtin_amdgcn_mfma_f32_16x16x32_bf16(aF[i], bF[j], a4[i][j], 0, 0, 0);
        }
#pragma unroll
        for (int j = 0; j < 2; ++j) {
            float bb = b4v[nc][j], wv = wov[nc][j];
#pragma unroll
            for (int i = 0; i < 4; ++i)
#pragma unroll
                for (int rr = 0; rr < 4; ++rr) {
                    float v = a4[i][j][rr] + bb;
                    v = v > 0.f ? v : 0.f;
                    pl[i][rr] += v * wv;
                }
        }
    }

    // ---- reduce: 16 col-lanes via shuffle, 4 waves via LDS, sigmoid store ----
    // scratch @24576 (dead h2 tail): disjoint from h3 [0,16384) and W4 bufs
    // [16384,24576), so lagging waves in P4 can't be disturbed.
    float* sc = (float*)&pool[SCO];
#pragma unroll
    for (int i = 0; i < 4; ++i)
#pragma unroll
        for (int rr = 0; rr < 4; ++rr) {
            float p = pl[i][rr];
            p += __shfl_xor(p, 1);
            p += __shfl_xor(p, 2);
            p += __shfl_xor(p, 4);
            p += __shfl_xor(p, 8);
            if (ln == 0) sc[w * 64 + i * 16 + q * 4 + rr] = p;
        }
    __syncthreads();   // vmcnt already 0 here; safe
    if (tid < 64) {
        float s = sc[tid] + sc[64 + tid] + sc[128 + tid] + sc[192 + tid];
        float lg = s + boutv;
        out[(size_t)(r0 + tid) * M_ + m] = 1.f / (1.f + __expf(-lg));
    }
}

// ---------------- host ----------------
extern "C" void kernel_launch(void* const* d_in, const int* in_sizes, int n_in,
                              void* d_out, int out_size, void* d_ws, size_t ws_size,
                              hipStream_t stream) {
    const float* x    = (const float*)d_in[0];
    const float* W0   = (const float*)d_in[1];
    const float* b0   = (const float*)d_in[2];
    const float* W1   = (const float*)d_in[3];
    const float* b1   = (const float*)d_in[4];
    const float* W2   = (const float*)d_in[5];
    const float* b2   = (const float*)d_in[6];
    const float* W3   = (const float*)d_in[7];
    const float* b3   = (const float*)d_in[8];
    const float* W4   = (const float*)d_in[9];
    const float* b4   = (const float*)d_in[10];
    const float* Wout = (const float*)d_in[11];
    const float* bout = (const float*)d_in[12];
    float* out = (float*)d_out;

    char* ws = (char*)d_ws;
    size_t off = 0;
    auto alloc = [&](size_t bytes) -> void* {
        off = (off + 255) & ~(size_t)255;
        void* p = ws + off;
        off += bytes;
        return p;
    };
    bf16* W0b = (bf16*)alloc((size_t)4096 * 4096 * 2);
    bf16* W1b = (bf16*)alloc((size_t)M_ * 64 * 32 * 2);
    bf16* W2b = (bf16*)alloc((size_t)M_ * 128 * 64 * 2);
    bf16* W3b = (bf16*)alloc((size_t)M_ * 256 * 128 * 2);
    bf16* W4b = (bf16*)alloc((size_t)M_ * 512 * 256 * 2);
    bf16* xb  = (bf16*)alloc((size_t)B_ * 4096 * 2);
    bf16* h0  = (bf16*)alloc((size_t)B_ * 4096 * 2);   // [B][128][32]

    CvtArgs ca;
    ca.src[0] = (const float4*)x;  ca.dst[0] = (short4*)xb;
    ca.src[1] = (const float4*)W0; ca.dst[1] = (short4*)W0b;
    ca.src[2] = (const float4*)W1; ca.dst[2] = (short4*)W1b;
    ca.src[3] = (const float4*)W2; ca.dst[3] = (short4*)W2b;
    ca.src[4] = (const float4*)W3; ca.dst[4] = (short4*)W3b;
    ca.src[5] = (const float4*)W4; ca.dst[5] = (short4*)W4b;
    cvt_all<<<(10813440 + 255) / 256, 256, 0, stream>>>(ca);

    {
        dim3 g(4096 / 64, B_ / 128, 1);
        gemm_l0<<<g, 256, 0, stream>>>(xb, W0b, b0, h0);
    }
    {
        dim3 g(B_ / 64, M_, 1);
        modules_fused<<<g, 256, 0, stream>>>(h0, W1b, b1, W2b, b2, W3b, b3,
                                             W4b, b4, Wout, bout, out);
    }
}

// Round 6
// 328.112 us; speedup vs baseline: 1.0786x; 1.0023x over previous
//
#include <hip/hip_runtime.h>
#include <hip/hip_bf16.h>

// MaskMLP R9: R8 shrunk to EXACTLY 48 KiB LDS -> 3 blocks/CU.
// R8 post-mortem: LDS_Block_Size 50176 B (49 KiB) still gave 2 blocks/CU
// (Occupancy 21%) while R5-R7's 49152 B gave 3 (29%) at same VGPR bracket
// -> LDS allocation granularity is coarse (>=8 KiB); 50176 rounds past the
// 3-block boundary. Fix: pool 25088 -> 24576 elems (49152 B exactly):
//   - h2: padded stride 136 -> xor16 chunk layout (8704 -> 8192 elems),
//     the layout proven correct in R5-R7's passing runs
//   - reduce scratch overlays dead W4-b0 @16384 (all LDS reads complete
//     at P4 round-31's final WAITL+BAR, all waves past it)
// Wait ledger / staging / math byte-identical to R8.
// Pool layout (bf16 elems), temporal overlays:
//   [0,4096)      W2 s0 (P2)   -> W3 s0 part (P3) -> h3 xor32 (P4)
//   [4096,8192)   W2 s1 (P2)   -> W3 s0 part      -> h3
//   [8192,10240)  W1 (P1)      -> W3 s1 part      -> h3
//   [10240,14848) h1 (P1->P2)  -> W3 s1 part      -> h3
//   [14848,16384) W3 s1 part   -> h3
//   [16384,18432) h0 (->P1)    -> h2 xor16 (P2->P3) -> W4 b0 (P4) -> scratch
//   [18432,20480)               h2               -> W4 b0
//   [20480,24576)               h2               -> W4 b1
// gemm_l0 / cvt_all unchanged.

using bf16 = __hip_bfloat16;
typedef short bf16x8 __attribute__((ext_vector_type(8)));   // 8 bf16 = 4 VGPRs
typedef float f32x4 __attribute__((ext_vector_type(4)));

constexpr int B_ = 1024;   // batch
constexpr int M_ = 128;    // modules

#define WAITV(N) asm volatile("s_waitcnt vmcnt(" #N ")" ::: "memory")
#define WAITL()  asm volatile("s_waitcnt lgkmcnt(0)" ::: "memory")
#define BAR()    asm volatile("s_barrier" ::: "memory")

// async global->LDS, 16B/lane; LDS dest = wave-uniform base + lane*16.
__device__ __forceinline__ void gload16_lds(const bf16* gp, bf16* lp) {
    __builtin_amdgcn_global_load_lds(
        (__attribute__((address_space(1))) void*)const_cast<bf16*>(gp),
        (__attribute__((address_space(3))) void*)lp,
        16, 0, 0);
}

// ---------------- fused fp32 -> bf16 conversion (x, W0..W4) ----------------
struct CvtArgs {
    const float4* src[6];
    short4* dst[6];
};
__global__ void cvt_all(CvtArgs a) {
    constexpr int starts[7] = {0, 1048576, 5242880, 5308416, 5570560,
                               6619136, 10813440};
    int i = blockIdx.x * blockDim.x + threadIdx.x;
    if (i >= starts[6]) return;
    int s = 0;
#pragma unroll
    for (int k = 1; k < 6; ++k) s += (i >= starts[k]) ? 1 : 0;
    int off = i - starts[s];
    float4 v = a.src[s][off];
    union { bf16 h[4]; short4 s4; } u;
    u.h[0] = __float2bfloat16(v.x);
    u.h[1] = __float2bfloat16(v.y);
    u.h[2] = __float2bfloat16(v.z);
    u.h[3] = __float2bfloat16(v.w);
    a.dst[s][off] = u.s4;
}

// ---------------- L0: h0 = relu(x @ W0^T + b0), K=4096 ----------------
// 128x64 tile, BK=64 (two 32-k halves per stage), 2 LDS sets, prefetch dist 2.
__global__ __launch_bounds__(256, 2)
void gemm_l0(const bf16* __restrict__ A, const bf16* __restrict__ W,
             const float* __restrict__ bias, bf16* __restrict__ C) {
    constexpr int LDA = 4096;
    __shared__ __align__(16) bf16 sA[2][2][128 * 32];   // [set][half][row*32]
    __shared__ __align__(16) bf16 sB[2][2][64 * 32];

    const int tid = threadIdx.x, w = tid >> 6, lane = tid & 63;
    const int q = lane >> 4, ln = lane & 15;
    const int lr = lane >> 2, lk = lane & 3;
    const int swz = (lk ^ (lr & 3)) * 8;
    const int wm = w >> 1, wn = w & 1;
    const int r0 = blockIdx.y * 128, c0 = blockIdx.x * 64;

    auto stage = [&](int s, int set) {   // 6 gloads/wave
        const int k0 = s * 64;
#pragma unroll
        for (int h = 0; h < 2; ++h) {
#pragma unroll
            for (int t = 0; t < 2; ++t) {
                int grp = w * 2 + t;
                gload16_lds(A + (size_t)(r0 + grp * 16 + lr) * LDA + k0 + h * 32 + swz,
                            &sA[set][h][grp * 512]);
            }
            gload16_lds(W + (size_t)(c0 + w * 16 + lr) * LDA + k0 + h * 32 + swz,
                        &sB[set][h][w * 512]);
        }
    };

    f32x4 acc[4][2];
#pragma unroll
    for (int i = 0; i < 4; ++i)
#pragma unroll
        for (int j = 0; j < 2; ++j) acc[i][j] = (f32x4){0.f, 0.f, 0.f, 0.f};

    stage(0, 0);
    stage(1, 1);
    for (int r = 0; r < 64; ++r) {
        if (r < 63) WAITV(6); else WAITV(0);   // current stage arrived
        BAR();
        const int set = r & 1;
        bf16x8 aF[2][4], bF[2][2];
#pragma unroll
        for (int h = 0; h < 2; ++h) {
#pragma unroll
            for (int i = 0; i < 4; ++i) {
                int row = wm * 64 + i * 16 + ln;
                aF[h][i] = *(const bf16x8*)&sA[set][h][row * 32 + ((q ^ (row & 3)) * 8)];
            }
#pragma unroll
            for (int j = 0; j < 2; ++j) {
                int rn = wn * 32 + j * 16 + ln;
                bF[h][j] = *(const bf16x8*)&sB[set][h][rn * 32 + ((q ^ (rn & 3)) * 8)];
            }
        }
        WAITL();
        BAR();                                  // release this set
        if (r + 2 < 64) stage(r + 2, set);      // refill just-freed set
#pragma unroll
        for (int h = 0; h < 2; ++h)
#pragma unroll
            for (int i = 0; i < 4; ++i)
#pragma unroll
                for (int j = 0; j < 2; ++j)
                    acc[i][j] = __builtin_amdgcn_mfma_f32_16x16x32_bf16(
                        aF[h][i], bF[h][j], acc[i][j], 0, 0, 0);
    }

#pragma unroll
    for (int j = 0; j < 2; ++j) {
        int col = c0 + wn * 32 + j * 16 + ln;
        float bv = bias[col];
#pragma unroll
        for (int i = 0; i < 4; ++i)
#pragma unroll
            for (int rr = 0; rr < 4; ++rr) {
                int row = r0 + wm * 64 + i * 16 + q * 4 + rr;
                float v = acc[i][j][rr] + bv;
                v = v > 0.f ? v : 0.f;
                C[(size_t)row * 4096 + col] = __float2bfloat16(v);
            }
    }
}

// ---------------- fused L1..L4 + Wout + sigmoid ----------------
// grid (16 strips, 128 modules), 4 waves, 48KB LDS -> 3 blocks/CU.
__global__ __launch_bounds__(256, 2)
void modules_fused(const bf16* __restrict__ h0g,
                   const bf16* __restrict__ W1b, const float* __restrict__ b1,
                   const bf16* __restrict__ W2b, const float* __restrict__ b2,
                   const bf16* __restrict__ W3b, const float* __restrict__ b3,
                   const bf16* __restrict__ W4b, const float* __restrict__ b4,
                   const float* __restrict__ Wout, const float* __restrict__ bout,
                   float* __restrict__ out) {
    constexpr int H3O = 0;          // h3 xor32, [0,16384)
    constexpr int W1B = 8192;       // W1 buf (P1), 2048
    constexpr int H1O = 10240;      // h1 stride 72, [10240,14848)
    constexpr int H0O = 16384;      // h0, [16384,18432)
    constexpr int H2O = 16384;      // h2 xor16, [16384,24576) (over dead h0)
    constexpr int P4B0 = 16384, P4B1 = 20480;   // W4 dbl bufs (over dead h2)
    constexpr int SCO = 16384;      // reduce scratch over dead W4 b0
    __shared__ __align__(16) bf16 pool[24576];  // 49152 B exactly

    const int tid = threadIdx.x, w = tid >> 6, lane = tid & 63;
    const int q = lane >> 4, ln = lane & 15;
    const int lr = lane >> 2, lk = lane & 3;
    const int swz = (lk ^ (lr & 3)) * 8;
    const int m = blockIdx.y;
    const int r0 = blockIdx.x * 64;

    const bf16* W1m = W1b + (size_t)m * 64 * 32;
    const bf16* W2m = W2b + (size_t)m * 128 * 64;
    const bf16* W3m = W3b + (size_t)m * 256 * 128;
    const bf16* W4m = W4b + (size_t)m * 512 * 256;

    auto stage = [&](const bf16* G, int ldg, int rows, int nr0, int k0, int woff) {
#pragma unroll
        for (int t = 0; t < rows / 64; ++t) {
            int r = t * 64 + w * 16 + lr;
            gload16_lds(G + (size_t)(nr0 + r) * ldg + k0 + swz,
                        pool + woff + t * 2048 + w * 512);
        }
    };
    auto rdA = [&](int hoff, int stride, int row, int kc) -> bf16x8 {
        return *(const bf16x8*)&pool[hoff + row * stride + kc * 8];
    };
    auto rdA0 = [&](int row) -> bf16x8 {   // h0, xor layout, kc = q
        return *(const bf16x8*)&pool[H0O + row * 32 + ((q ^ (row & 3)) * 8)];
    };
    auto rdB = [&](int woff, int rn) -> bf16x8 {
        return *(const bf16x8*)&pool[woff + rn * 32 + ((q ^ (rn & 3)) * 8)];
    };
    auto wrH = [&](int hoff, int stride, int row, int col, float v) {
        pool[hoff + row * stride + col] = __float2bfloat16(v);
    };
    // h2 xor16 layout: elem = row*128 + ((col>>3)^(row&7))*8 + (col&7)
    auto wrH2 = [&](int row, int col, float v) {
        pool[H2O + row * 128 + (((col >> 3) ^ (row & 7)) * 8) + (col & 7)] =
            __float2bfloat16(v);
    };
    auto rdA2 = [&](int row, int kc) -> bf16x8 {
        return *(const bf16x8*)&pool[H2O + row * 128 + ((kc ^ (row & 7)) * 8)];
    };
    // h3 xor32 layout: elem = row*256 + ((col>>3)^(row&7))*8 + (col&7)
    auto wrH3 = [&](int row, int col, float v) {
        pool[H3O + row * 256 + (((col >> 3) ^ (row & 7)) * 8) + (col & 7)] =
            __float2bfloat16(v);
    };
    auto rdA3 = [&](int row, int kc) -> bf16x8 {
        return *(const bf16x8*)&pool[H3O + row * 256 + ((kc ^ (row & 7)) * 8)];
    };

    // ---- preload all epilogue scalars, then drain vmcnt so counts are exact
    float b1v = b1[m * 64 + w * 16 + ln];
    float b2v[2], b3v[4], b4v[4][2], wov[4][2];
#pragma unroll
    for (int j = 0; j < 2; ++j) b2v[j] = b2[m * 128 + w * 32 + j * 16 + ln];
#pragma unroll
    for (int j = 0; j < 4; ++j) b3v[j] = b3[m * 256 + w * 64 + j * 16 + ln];
#pragma unroll
    for (int nc = 0; nc < 4; ++nc)
#pragma unroll
        for (int j = 0; j < 2; ++j) {
            int col = nc * 128 + w * 32 + j * 16 + ln;
            b4v[nc][j] = b4[(size_t)m * 512 + col];
            wov[nc][j] = Wout[(size_t)m * 512 + col];
        }
    float boutv = bout[m];
    WAITV(0);

    // ---- issue: h0 strip (1), W1 (1), P2 s0 (2), P2 s1 (2) -> out=6
    gload16_lds(h0g + (size_t)(r0 + w * 16 + lr) * 4096 + m * 32 + swz,
                pool + H0O + w * 512);
    stage(W1m, 32, 64, 0, 0, W1B);
    stage(W2m, 64, 128, 0, 0, 0);
    stage(W2m, 64, 128, 0, 32, 4096);

    // ================= P1: h1 = relu(h0 @ W1^T + b1) =================
    WAITV(4);   // h0 + W1 arrived; P2 stages remain in flight
    BAR();
    {
        bf16x8 aF[4], bF;
#pragma unroll
        for (int i = 0; i < 4; ++i) aF[i] = rdA0(i * 16 + ln);
        bF = rdB(W1B, w * 16 + ln);
        WAITL();
        BAR();
        f32x4 a1[4];
#pragma unroll
        for (int i = 0; i < 4; ++i) {
            a1[i] = (f32x4){0.f, 0.f, 0.f, 0.f};
            a1[i] = __builtin_amdgcn_mfma_f32_16x16x32_bf16(aF[i], bF, a1[i], 0, 0, 0);
        }
        int col = w * 16 + ln;
#pragma unroll
        for (int i = 0; i < 4; ++i)
#pragma unroll
            for (int rr = 0; rr < 4; ++rr) {
                float v = a1[i][rr] + b1v;
                v = v > 0.f ? v : 0.f;
                wrH(H1O, 72, i * 16 + q * 4 + rr, col, v);
            }
        WAITL();
        BAR();   // h1 visible
    }

    // ================= P2: h2 = relu(h1 @ W2^T + b2), 2 rounds =================
    {
        f32x4 a2[4][2];
#pragma unroll
        for (int i = 0; i < 4; ++i)
#pragma unroll
            for (int j = 0; j < 2; ++j) a2[i][j] = (f32x4){0.f, 0.f, 0.f, 0.f};
#pragma unroll
        for (int kr = 0; kr < 2; ++kr) {
            if (kr == 0) WAITV(2); else WAITV(0);
            BAR();
            bf16x8 aF[4], bF[2];
#pragma unroll
            for (int i = 0; i < 4; ++i) aF[i] = rdA(H1O, 72, i * 16 + ln, kr * 4 + q);
#pragma unroll
            for (int j = 0; j < 2; ++j) bF[j] = rdB(kr * 4096, w * 32 + j * 16 + ln);
            WAITL();
            BAR();
            if (kr == 1) {               // P3 s0,s1 (4+4) over consumed P2 bufs + dead W1/h1
                stage(W3m, 128, 256, 0, 0, 0);
                stage(W3m, 128, 256, 0, 32, 8192);
            }
#pragma unroll
            for (int i = 0; i < 4; ++i)
#pragma unroll
                for (int j = 0; j < 2; ++j)
                    a2[i][j] = __builtin_amdgcn_mfma_f32_16x16x32_bf16(aF[i], bF[j], a2[i][j], 0, 0, 0);
        }
#pragma unroll
        for (int j = 0; j < 2; ++j) {
            int col = w * 32 + j * 16 + ln;
#pragma unroll
            for (int i = 0; i < 4; ++i)
#pragma unroll
                for (int rr = 0; rr < 4; ++rr) {
                    float v = a2[i][j][rr] + b2v[j];
                    v = v > 0.f ? v : 0.f;
                    wrH2(i * 16 + q * 4 + rr, col, v);
                }
        }
        WAITL();
        BAR();   // h2 visible (over dead h0)
    }

    // ================= P3: h3 = relu(h2 @ W3^T + b3), 4 rounds, dist-1 =================
    {
        f32x4 a3[4][4];
#pragma unroll
        for (int i = 0; i < 4; ++i)
#pragma unroll
            for (int j = 0; j < 4; ++j) a3[i][j] = (f32x4){0.f, 0.f, 0.f, 0.f};
#pragma unroll
        for (int kr = 0; kr < 4; ++kr) {
            if (kr < 3) WAITV(4); else WAITV(0);
            BAR();
            bf16x8 aF[4], bF[4];
#pragma unroll
            for (int i = 0; i < 4; ++i) aF[i] = rdA2(i * 16 + ln, kr * 4 + q);
#pragma unroll
            for (int j = 0; j < 4; ++j) bF[j] = rdB((kr & 1) * 8192, w * 64 + j * 16 + ln);
            WAITL();
            BAR();
            if (kr == 0)      stage(W3m, 128, 256, 0, 64, 0);       // s2
            else if (kr == 1) stage(W3m, 128, 256, 0, 96, 8192);    // s3
            else if (kr == 3) {                                     // P4 s0,s1 (2+2)
                stage(W4m, 256, 128, 0, 0, P4B0);
                stage(W4m, 256, 128, 0, 32, P4B1);
            }
#pragma unroll
            for (int i = 0; i < 4; ++i)
#pragma unroll
                for (int j = 0; j < 4; ++j)
                    a3[i][j] = __builtin_amdgcn_mfma_f32_16x16x32_bf16(aF[i], bF[j], a3[i][j], 0, 0, 0);
        }
        // h3 (xor32) over dead W3 bufs: all bF reads drained at kr=3's WAITL+BAR
#pragma unroll
        for (int j = 0; j < 4; ++j) {
            int col = w * 64 + j * 16 + ln;
#pragma unroll
            for (int i = 0; i < 4; ++i)
#pragma unroll
                for (int rr = 0; rr < 4; ++rr) {
                    float v = a3[i][j][rr] + b3v[j];
                    v = v > 0.f ? v : 0.f;
                    wrH3(i * 16 + q * 4 + rr, col, v);
                }
        }
        WAITL();
        BAR();   // h3 visible
    }

    // == P4: L4 (512 cols in 4 nc-chunks of 128) + Wout dot; dbl-buf dist-1 ==
    // Round r reads buf[r&1], then (after WAITL+BAR) restages tile r+2 into
    // the same buf. Entry: s_r done, s_{r+1} in flight -> WAITV(2); last drains.
    float pl[4][4];
#pragma unroll
    for (int i = 0; i < 4; ++i)
#pragma unroll
        for (int rr = 0; rr < 4; ++rr) pl[i][rr] = 0.f;

#pragma unroll
    for (int nc = 0; nc < 4; ++nc) {
        f32x4 a4[4][2];
#pragma unroll
        for (int i = 0; i < 4; ++i)
#pragma unroll
            for (int j = 0; j < 2; ++j) a4[i][j] = (f32x4){0.f, 0.f, 0.f, 0.f};
#pragma unroll
        for (int kr = 0; kr < 8; ++kr) {
            const int r = nc * 8 + kr;
            if (r < 31) WAITV(2); else WAITV(0);
            BAR();
            const int wb = (r & 1) ? P4B1 : P4B0;
            bf16x8 aF[4], bF[2];
#pragma unroll
            for (int i = 0; i < 4; ++i) aF[i] = rdA3(i * 16 + ln, kr * 4 + q);
#pragma unroll
            for (int j = 0; j < 2; ++j) bF[j] = rdB(wb, w * 32 + j * 16 + ln);
            WAITL();
            BAR();
            if (r + 2 < 32) {   // restage just-read buffer with tile r+2
                const int r2 = r + 2;
                stage(W4m, 256, 128, (r2 >> 3) * 128, (r2 & 7) * 32, wb);
            }
#pragma unroll
            for (int i = 0; i < 4; ++i)
#pragma unroll
                for (int j = 0; j < 2; ++j)
                    a4[i][j] = __builtin_amdgcn_mfma_f32_16x16x32_bf16(aF[i], bF[j], a4[i][j], 0, 0, 0);
        }
#pragma unroll
        for (int j = 0; j < 2; ++j) {
            float bb = b4v[nc][j], wv = wov[nc][j];
#pragma unroll
            for (int i = 0; i < 4; ++i)
#pragma unroll
                for (int rr = 0; rr < 4; ++rr) {
                    float v = a4[i][j][rr] + bb;
                    v = v > 0.f ? v : 0.f;
                    pl[i][rr] += v * wv;
                }
        }
    }

    // ---- reduce: 16 col-lanes via shuffle, 4 waves via LDS, sigmoid store ----
    // scratch @16384 over dead W4 b0: every wave passed P4 round-31's final
    // WAITL+BAR, after which no LDS read of W4 bufs or h3 occurs.
    float* sc = (float*)&pool[SCO];
#pragma unroll
    for (int i = 0; i < 4; ++i)
#pragma unroll
        for (int rr = 0; rr < 4; ++rr) {
            float p = pl[i][rr];
            p += __shfl_xor(p, 1);
            p += __shfl_xor(p, 2);
            p += __shfl_xor(p, 4);
            p += __shfl_xor(p, 8);
            if (ln == 0) sc[w * 64 + i * 16 + q * 4 + rr] = p;
        }
    __syncthreads();   // vmcnt already 0 here; safe
    if (tid < 64) {
        float s = sc[tid] + sc[64 + tid] + sc[128 + tid] + sc[192 + tid];
        float lg = s + boutv;
        out[(size_t)(r0 + tid) * M_ + m] = 1.f / (1.f + __expf(-lg));
    }
}

// ---------------- host ----------------
extern "C" void kernel_launch(void* const* d_in, const int* in_sizes, int n_in,
                              void* d_out, int out_size, void* d_ws, size_t ws_size,
                              hipStream_t stream) {
    const float* x    = (const float*)d_in[0];
    const float* W0   = (const float*)d_in[1];
    const float* b0   = (const float*)d_in[2];
    const float* W1   = (const float*)d_in[3];
    const float* b1   = (const float*)d_in[4];
    const float* W2   = (const float*)d_in[5];
    const float* b2   = (const float*)d_in[6];
    const float* W3   = (const float*)d_in[7];
    const float* b3   = (const float*)d_in[8];
    const float* W4   = (const float*)d_in[9];
    const float* b4   = (const float*)d_in[10];
    const float* Wout = (const float*)d_in[11];
    const float* bout = (const float*)d_in[12];
    float* out = (float*)d_out;

    char* ws = (char*)d_ws;
    size_t off = 0;
    auto alloc = [&](size_t bytes) -> void* {
        off = (off + 255) & ~(size_t)255;
        void* p = ws + off;
        off += bytes;
        return p;
    };
    bf16* W0b = (bf16*)alloc((size_t)4096 * 4096 * 2);
    bf16* W1b = (bf16*)alloc((size_t)M_ * 64 * 32 * 2);
    bf16* W2b = (bf16*)alloc((size_t)M_ * 128 * 64 * 2);
    bf16* W3b = (bf16*)alloc((size_t)M_ * 256 * 128 * 2);
    bf16* W4b = (bf16*)alloc((size_t)M_ * 512 * 256 * 2);
    bf16* xb  = (bf16*)alloc((size_t)B_ * 4096 * 2);
    bf16* h0  = (bf16*)alloc((size_t)B_ * 4096 * 2);   // [B][128][32]

    CvtArgs ca;
    ca.src[0] = (const float4*)x;  ca.dst[0] = (short4*)xb;
    ca.src[1] = (const float4*)W0; ca.dst[1] = (short4*)W0b;
    ca.src[2] = (const float4*)W1; ca.dst[2] = (short4*)W1b;
    ca.src[3] = (const float4*)W2; ca.dst[3] = (short4*)W2b;
    ca.src[4] = (const float4*)W3; ca.dst[4] = (short4*)W3b;
    ca.src[5] = (const float4*)W4; ca.dst[5] = (short4*)W4b;
    cvt_all<<<(10813440 + 255) / 256, 256, 0, stream>>>(ca);

    {
        dim3 g(4096 / 64, B_ / 128, 1);
        gemm_l0<<<g, 256, 0, stream>>>(xb, W0b, b0, h0);
    }
    {
        dim3 g(B_ / 64, M_, 1);
        modules_fused<<<g, 256, 0, stream>>>(h0, W1b, b1, W2b, b2, W3b, b3,
                                             W4b, b4, Wout, bout, out);
    }
}

// Round 7
// 321.531 us; speedup vs baseline: 1.1007x; 1.0205x over previous
//
#include <hip/hip_runtime.h>
#include <hip/hip_bf16.h>

// MaskMLP R10: wave-private weight staging -> barrier-free K-rounds.
// R4-R9 post-mortem: MfmaUtil~20/VALUBusy~25 at every occupancy tried; the
// invariant cost is ~78 s_barriers/block (2 per 8-MFMA K-round). Key fact:
// every W row a wave consumes is consumed ONLY by that wave (rn = w*...),
// so cross-wave sync around W staging is pure overhead. R10 keeps gload_lds
// staging (codegen proven clean: WRITE 512KB, VGPR 92) but each wave stages
// its own rows into a wave-PRIVATE LDS region; producer==consumer, so
// s_waitcnt vmcnt(N) alone orders gload->ds_read. Barriers only at shared
// activation hand-offs: 8 total (was ~78). P3/P4 K-rounds: zero barriers,
// dist-2 private double-buffers.
// Pool (bf16 elems, 24576 = 48KB), temporal overlays:
//   B=[0,8192):    h2 xor16 (P2->P3) -> W4 priv dbuf w*2048+(r&1)*1024 (P4)
//                  -> reduce scratch
//   A=[8192,24576): P1/P2: W1priv@8192(w*512) W2priv@10240(w*2048+kr*1024)
//                         h0@18432(w*512) h1@20480 xor8
//                  P3: W3priv 8192+w*4096+(kr&1)*2048
//                  P4: h3 xor32 @8192 (after barrier releases W3priv)
// gemm_l0 / cvt_all unchanged.

using bf16 = __hip_bfloat16;
typedef short bf16x8 __attribute__((ext_vector_type(8)));   // 8 bf16 = 4 VGPRs
typedef float f32x4 __attribute__((ext_vector_type(4)));

constexpr int B_ = 1024;   // batch
constexpr int M_ = 128;    // modules

#define WAITV(N) asm volatile("s_waitcnt vmcnt(" #N ")" ::: "memory")
#define WAITL()  asm volatile("s_waitcnt lgkmcnt(0)" ::: "memory")
#define BAR()    asm volatile("s_barrier" ::: "memory")

// async global->LDS, 16B/lane; LDS dest = wave-uniform base + lane*16.
__device__ __forceinline__ void gload16_lds(const bf16* gp, bf16* lp) {
    __builtin_amdgcn_global_load_lds(
        (__attribute__((address_space(1))) void*)const_cast<bf16*>(gp),
        (__attribute__((address_space(3))) void*)lp,
        16, 0, 0);
}

// ---------------- fused fp32 -> bf16 conversion (x, W0..W4) ----------------
struct CvtArgs {
    const float4* src[6];
    short4* dst[6];
};
__global__ void cvt_all(CvtArgs a) {
    constexpr int starts[7] = {0, 1048576, 5242880, 5308416, 5570560,
                               6619136, 10813440};
    int i = blockIdx.x * blockDim.x + threadIdx.x;
    if (i >= starts[6]) return;
    int s = 0;
#pragma unroll
    for (int k = 1; k < 6; ++k) s += (i >= starts[k]) ? 1 : 0;
    int off = i - starts[s];
    float4 v = a.src[s][off];
    union { bf16 h[4]; short4 s4; } u;
    u.h[0] = __float2bfloat16(v.x);
    u.h[1] = __float2bfloat16(v.y);
    u.h[2] = __float2bfloat16(v.z);
    u.h[3] = __float2bfloat16(v.w);
    a.dst[s][off] = u.s4;
}

// ---------------- L0: h0 = relu(x @ W0^T + b0), K=4096 ----------------
// 128x64 tile, BK=64 (two 32-k halves per stage), 2 LDS sets, prefetch dist 2.
__global__ __launch_bounds__(256, 2)
void gemm_l0(const bf16* __restrict__ A, const bf16* __restrict__ W,
             const float* __restrict__ bias, bf16* __restrict__ C) {
    constexpr int LDA = 4096;
    __shared__ __align__(16) bf16 sA[2][2][128 * 32];   // [set][half][row*32]
    __shared__ __align__(16) bf16 sB[2][2][64 * 32];

    const int tid = threadIdx.x, w = tid >> 6, lane = tid & 63;
    const int q = lane >> 4, ln = lane & 15;
    const int lr = lane >> 2, lk = lane & 3;
    const int swz = (lk ^ (lr & 3)) * 8;
    const int wm = w >> 1, wn = w & 1;
    const int r0 = blockIdx.y * 128, c0 = blockIdx.x * 64;

    auto stage = [&](int s, int set) {   // 6 gloads/wave
        const int k0 = s * 64;
#pragma unroll
        for (int h = 0; h < 2; ++h) {
#pragma unroll
            for (int t = 0; t < 2; ++t) {
                int grp = w * 2 + t;
                gload16_lds(A + (size_t)(r0 + grp * 16 + lr) * LDA + k0 + h * 32 + swz,
                            &sA[set][h][grp * 512]);
            }
            gload16_lds(W + (size_t)(c0 + w * 16 + lr) * LDA + k0 + h * 32 + swz,
                        &sB[set][h][w * 512]);
        }
    };

    f32x4 acc[4][2];
#pragma unroll
    for (int i = 0; i < 4; ++i)
#pragma unroll
        for (int j = 0; j < 2; ++j) acc[i][j] = (f32x4){0.f, 0.f, 0.f, 0.f};

    stage(0, 0);
    stage(1, 1);
    for (int r = 0; r < 64; ++r) {
        if (r < 63) WAITV(6); else WAITV(0);   // current stage arrived
        BAR();
        const int set = r & 1;
        bf16x8 aF[2][4], bF[2][2];
#pragma unroll
        for (int h = 0; h < 2; ++h) {
#pragma unroll
            for (int i = 0; i < 4; ++i) {
                int row = wm * 64 + i * 16 + ln;
                aF[h][i] = *(const bf16x8*)&sA[set][h][row * 32 + ((q ^ (row & 3)) * 8)];
            }
#pragma unroll
            for (int j = 0; j < 2; ++j) {
                int rn = wn * 32 + j * 16 + ln;
                bF[h][j] = *(const bf16x8*)&sB[set][h][rn * 32 + ((q ^ (rn & 3)) * 8)];
            }
        }
        WAITL();
        BAR();                                  // release this set
        if (r + 2 < 64) stage(r + 2, set);      // refill just-freed set
#pragma unroll
        for (int h = 0; h < 2; ++h)
#pragma unroll
            for (int i = 0; i < 4; ++i)
#pragma unroll
                for (int j = 0; j < 2; ++j)
                    acc[i][j] = __builtin_amdgcn_mfma_f32_16x16x32_bf16(
                        aF[h][i], bF[h][j], acc[i][j], 0, 0, 0);
    }

#pragma unroll
    for (int j = 0; j < 2; ++j) {
        int col = c0 + wn * 32 + j * 16 + ln;
        float bv = bias[col];
#pragma unroll
        for (int i = 0; i < 4; ++i)
#pragma unroll
            for (int rr = 0; rr < 4; ++rr) {
                int row = r0 + wm * 64 + i * 16 + q * 4 + rr;
                float v = acc[i][j][rr] + bv;
                v = v > 0.f ? v : 0.f;
                C[(size_t)row * 4096 + col] = __float2bfloat16(v);
            }
    }
}

// ---------------- fused L1..L4 + Wout + sigmoid ----------------
// grid (16 strips, 128 modules), 4 waves, 48KB LDS.
__global__ __launch_bounds__(256, 2)
void modules_fused(const bf16* __restrict__ h0g,
                   const bf16* __restrict__ W1b, const float* __restrict__ b1,
                   const bf16* __restrict__ W2b, const float* __restrict__ b2,
                   const bf16* __restrict__ W3b, const float* __restrict__ b3,
                   const bf16* __restrict__ W4b, const float* __restrict__ b4,
                   const float* __restrict__ Wout, const float* __restrict__ bout,
                   float* __restrict__ out) {
    constexpr int H2O = 0;          // h2 xor16, [0,8192)
    constexpr int W4P = 0;          // W4 priv dbuf over dead h2: w*2048+(r&1)*1024
    constexpr int SCO = 0;          // reduce scratch over dead W4 (post-barrier)
    constexpr int W1B = 8192;       // W1 priv, w*512, [8192,10240)
    constexpr int W2B = 10240;      // W2 priv, w*2048+kr*1024, [10240,18432)
    constexpr int H0O = 18432;      // h0, w*512, [18432,20480)
    constexpr int H1O = 20480;      // h1 xor8, [20480,24576)
    constexpr int W3P = 8192;       // W3 priv (P3), 8192+w*4096+(kr&1)*2048
    constexpr int H3O = 8192;       // h3 xor32 (P4), [8192,24576) over dead W3
    __shared__ __align__(16) bf16 pool[24576];  // 49152 B

    const int tid = threadIdx.x, w = tid >> 6, lane = tid & 63;
    const int q = lane >> 4, ln = lane & 15;
    const int lr = lane >> 2, lk = lane & 3;
    const int swz = (lk ^ (lr & 3)) * 8;
    const int m = blockIdx.y;
    const int r0 = blockIdx.x * 64;

    const bf16* W1m = W1b + (size_t)m * 64 * 32;
    const bf16* W2m = W2b + (size_t)m * 128 * 64;
    const bf16* W3m = W3b + (size_t)m * 256 * 128;
    const bf16* W4m = W4b + (size_t)m * 512 * 256;

    // stage nt*16 rows x 32 cols of G (from grow0, col k0) into private LDS
    // at dstOff (wave-uniform). Source pre-swizzled so linear LDS + swizzled
    // read are conflict-reduced (both-sides rule).
    auto stageW = [&](const bf16* G, int ldg, int grow0, int k0, int dstOff,
                      int nt) {
#pragma unroll
        for (int t = 0; t < 4; ++t)
            if (t < nt)
                gload16_lds(G + (size_t)(grow0 + t * 16 + lr) * ldg + k0 + swz,
                            pool + dstOff + t * 512);
    };
    // private W fragment: local row rn (16/32/64 rows), 32-col buf
    auto rdB = [&](int off, int rn) -> bf16x8 {
        return *(const bf16x8*)&pool[off + rn * 32 + ((q ^ (rn & 3)) * 8)];
    };
    auto rdA0 = [&](int row) -> bf16x8 {   // h0, gload pre-swizzle layout
        return *(const bf16x8*)&pool[H0O + row * 32 + ((q ^ (row & 3)) * 8)];
    };
    // h1: 64x64 xor8
    auto wrH1 = [&](int row, int col, float v) {
        pool[H1O + row * 64 + (((col >> 3) ^ (row & 7)) * 8) + (col & 7)] =
            __float2bfloat16(v);
    };
    auto rdA1 = [&](int row, int kc) -> bf16x8 {
        return *(const bf16x8*)&pool[H1O + row * 64 + ((kc ^ (row & 7)) * 8)];
    };
    // h2: 64x128 xor16
    auto wrH2 = [&](int row, int col, float v) {
        pool[H2O + row * 128 + (((col >> 3) ^ (row & 7)) * 8) + (col & 7)] =
            __float2bfloat16(v);
    };
    auto rdA2 = [&](int row, int kc) -> bf16x8 {
        return *(const bf16x8*)&pool[H2O + row * 128 + ((kc ^ (row & 7)) * 8)];
    };
    // h3: 64x256 xor32
    auto wrH3 = [&](int row, int col, float v) {
        pool[H3O + row * 256 + (((col >> 3) ^ (row & 7)) * 8) + (col & 7)] =
            __float2bfloat16(v);
    };
    auto rdA3 = [&](int row, int kc) -> bf16x8 {
        return *(const bf16x8*)&pool[H3O + row * 256 + ((kc ^ (row & 7)) * 8)];
    };

    // ---- preload epilogue scalars, then drain vmcnt so counts are exact
    float b1v = b1[m * 64 + w * 16 + ln];
    float b2v[2], b3v[4], b4v[4][2], wov[4][2];
#pragma unroll
    for (int j = 0; j < 2; ++j) b2v[j] = b2[m * 128 + w * 32 + j * 16 + ln];
#pragma unroll
    for (int j = 0; j < 4; ++j) b3v[j] = b3[m * 256 + w * 64 + j * 16 + ln];
#pragma unroll
    for (int nc = 0; nc < 4; ++nc)
#pragma unroll
        for (int j = 0; j < 2; ++j) {
            int col = nc * 128 + w * 32 + j * 16 + ln;
            b4v[nc][j] = b4[(size_t)m * 512 + col];
            wov[nc][j] = Wout[(size_t)m * 512 + col];
        }
    float boutv = bout[m];
    WAITV(0);

    // ---- issue: h0 strip (1, shared), W1 priv (1), W2 priv r0+r1 (2+2) -> 6
    gload16_lds(h0g + (size_t)(r0 + w * 16 + lr) * 4096 + m * 32 + swz,
                pool + H0O + w * 512);
    stageW(W1m, 32, w * 16, 0, W1B + w * 512, 1);
    stageW(W2m, 64, w * 32, 0,  W2B + w * 2048, 2);
    stageW(W2m, 64, w * 32, 32, W2B + w * 2048 + 1024, 2);

    // ================= P1: h1 = relu(h0 @ W1^T + b1) =================
    WAITV(4);   // own h0 + W1 landed; W2 (4) in flight. BAR -> ALL h0 visible.
    BAR();
    {
        f32x4 a1[4];
#pragma unroll
        for (int i = 0; i < 4; ++i) {
            a1[i] = (f32x4){0.f, 0.f, 0.f, 0.f};
            a1[i] = __builtin_amdgcn_mfma_f32_16x16x32_bf16(
                rdA0(i * 16 + ln), rdB(W1B + w * 512, ln), a1[i], 0, 0, 0);
        }
        int col = w * 16 + ln;
#pragma unroll
        for (int i = 0; i < 4; ++i)
#pragma unroll
            for (int rr = 0; rr < 4; ++rr) {
                float v = a1[i][rr] + b1v;
                wrH1(i * 16 + q * 4 + rr, col, v > 0.f ? v : 0.f);
            }
        WAITL();
        BAR();   // h1 visible
    }

    // ===== P2: h2 = relu(h1 @ W2^T + b2), 2 rounds, NO intra barriers =====
    {
        f32x4 a2[4][2];
#pragma unroll
        for (int i = 0; i < 4; ++i)
#pragma unroll
            for (int j = 0; j < 2; ++j) a2[i][j] = (f32x4){0.f, 0.f, 0.f, 0.f};
#pragma unroll
        for (int kr = 0; kr < 2; ++kr) {
            if (kr == 0) WAITV(2); else WAITV(0);   // own W2 round landed
            bf16x8 aF[4], bF[2];
#pragma unroll
            for (int i = 0; i < 4; ++i) aF[i] = rdA1(i * 16 + ln, kr * 4 + q);
#pragma unroll
            for (int j = 0; j < 2; ++j)
                bF[j] = rdB(W2B + w * 2048 + kr * 1024, j * 16 + ln);
#pragma unroll
            for (int i = 0; i < 4; ++i)
#pragma unroll
                for (int j = 0; j < 2; ++j)
                    a2[i][j] = __builtin_amdgcn_mfma_f32_16x16x32_bf16(
                        aF[i], bF[j], a2[i][j], 0, 0, 0);
        }
        WAITL();
        BAR();   // all waves done reading h1/W2/h0 -> A-region released
        // issue W3 priv rounds 0,1 into own A slice (over dead W1/W2/h0/h1)
        stageW(W3m, 128, w * 64, 0,  W3P + w * 4096, 4);
        stageW(W3m, 128, w * 64, 32, W3P + w * 4096 + 2048, 4);
        // h2 epilogue into B (nobody reads B yet)
#pragma unroll
        for (int j = 0; j < 2; ++j) {
            int col = w * 32 + j * 16 + ln;
#pragma unroll
            for (int i = 0; i < 4; ++i)
#pragma unroll
                for (int rr = 0; rr < 4; ++rr) {
                    float v = a2[i][j][rr] + b2v[j];
                    wrH2(i * 16 + q * 4 + rr, col, v > 0.f ? v : 0.f);
                }
        }
        WAITL();
        BAR();   // h2 visible
    }

    // == P3: h3 = relu(h2 @ W3^T + b3), 4 rounds, priv dist-2, NO barriers ==
    {
        f32x4 a3[4][4];
#pragma unroll
        for (int i = 0; i < 4; ++i)
#pragma unroll
            for (int j = 0; j < 4; ++j) a3[i][j] = (f32x4){0.f, 0.f, 0.f, 0.f};
#pragma unroll
        for (int kr = 0; kr < 4; ++kr) {
            if (kr < 3) WAITV(4); else WAITV(0);   // own round-kr loads landed
            const int buf = W3P + w * 4096 + (kr & 1) * 2048;
            bf16x8 aF[4], bF[4];
#pragma unroll
            for (int i = 0; i < 4; ++i) aF[i] = rdA2(i * 16 + ln, kr * 4 + q);
#pragma unroll
            for (int j = 0; j < 4; ++j) bF[j] = rdB(buf, j * 16 + ln);
            WAITL();   // own reads retired -> safe to overwrite this buf
            if (kr < 2)
                stageW(W3m, 128, w * 64, (kr + 2) * 32, buf, 4);
#pragma unroll
            for (int i = 0; i < 4; ++i)
#pragma unroll
                for (int j = 0; j < 4; ++j)
                    a3[i][j] = __builtin_amdgcn_mfma_f32_16x16x32_bf16(
                        aF[i], bF[j], a3[i][j], 0, 0, 0);
        }
        BAR();   // all waves done reading W3priv + h2
        // prime W4 priv rounds 0,1 into B (over dead h2)
        stageW(W4m, 256, w * 32, 0,  W4P + w * 2048, 2);
        stageW(W4m, 256, w * 32, 32, W4P + w * 2048 + 1024, 2);
        // h3 epilogue over dead W3priv
#pragma unroll
        for (int j = 0; j < 4; ++j) {
            int col = w * 64 + j * 16 + ln;
#pragma unroll
            for (int i = 0; i < 4; ++i)
#pragma unroll
                for (int rr = 0; rr < 4; ++rr) {
                    float v = a3[i][j][rr] + b3v[j];
                    wrH3(i * 16 + q * 4 + rr, col, v > 0.f ? v : 0.f);
                }
        }
        WAITL();
        BAR();   // h3 visible (W4 loads still in flight: vmcnt=4)
    }

    // == P4: 32 rounds, priv dist-2 dbuf, ZERO barriers ==
    float pl[4][4];
#pragma unroll
    for (int i = 0; i < 4; ++i)
#pragma unroll
        for (int rr = 0; rr < 4; ++rr) pl[i][rr] = 0.f;

#pragma unroll
    for (int nc = 0; nc < 4; ++nc) {
        f32x4 a4[4][2];
#pragma unroll
        for (int i = 0; i < 4; ++i)
#pragma unroll
            for (int j = 0; j < 2; ++j) a4[i][j] = (f32x4){0.f, 0.f, 0.f, 0.f};
#pragma unroll
        for (int kr = 0; kr < 8; ++kr) {
            const int r = nc * 8 + kr;
            if (r < 31) WAITV(2); else WAITV(0);   // own round-r pair landed
            const int buf = W4P + w * 2048 + (r & 1) * 1024;
            bf16x8 aF[4], bF[2];
#pragma unroll
            for (int i = 0; i < 4; ++i) aF[i] = rdA3(i * 16 + ln, kr * 4 + q);
#pragma unroll
            for (int j = 0; j < 2; ++j) bF[j] = rdB(buf, j * 16 + ln);
            WAITL();   // own reads retired -> safe to refill this buf
            if (r + 2 < 32) {
                const int r2 = r + 2;
                stageW(W4m, 256, (r2 >> 3) * 128 + w * 32, (r2 & 7) * 32, buf, 2);
            }
#pragma unroll
            for (int i = 0; i < 4; ++i)
#pragma unroll
                for (int j = 0; j < 2; ++j)
                    a4[i][j] = __builtin_amdgcn_mfma_f32_16x16x32_bf16(
                        aF[i], bF[j], a4[i][j], 0, 0, 0);
        }
#pragma unroll
        for (int j = 0; j < 2; ++j) {
            float bb = b4v[nc][j], wv = wov[nc][j];
#pragma unroll
            for (int i = 0; i < 4; ++i)
#pragma unroll
                for (int rr = 0; rr < 4; ++rr) {
                    float v = a4[i][j][rr] + bb;
                    v = v > 0.f ? v : 0.f;
                    pl[i][rr] += v * wv;
                }
        }
    }

    // ---- reduce: 16 col-lanes via shuffle, 4 waves via LDS, sigmoid store ----
    BAR();   // all waves past P4 (h3 + all W4 bufs dead) -> scratch safe
    float* sc = (float*)&pool[SCO];
#pragma unroll
    for (int i = 0; i < 4; ++i)
#pragma unroll
        for (int rr = 0; rr < 4; ++rr) {
            float p = pl[i][rr];
            p += __shfl_xor(p, 1);
            p += __shfl_xor(p, 2);
            p += __shfl_xor(p, 4);
            p += __shfl_xor(p, 8);
            if (ln == 0) sc[w * 64 + i * 16 + q * 4 + rr] = p;
        }
    __syncthreads();   // vmcnt already 0; lgkm drained by syncthreads
    if (tid < 64) {
        float s = sc[tid] + sc[64 + tid] + sc[128 + tid] + sc[192 + tid];
        float lg = s + boutv;
        out[(size_t)(r0 + tid) * M_ + m] = 1.f / (1.f + __expf(-lg));
    }
}

// ---------------- host ----------------
extern "C" void kernel_launch(void* const* d_in, const int* in_sizes, int n_in,
                              void* d_out, int out_size, void* d_ws, size_t ws_size,
                              hipStream_t stream) {
    const float* x    = (const float*)d_in[0];
    const float* W0   = (const float*)d_in[1];
    const float* b0   = (const float*)d_in[2];
    const float* W1   = (const float*)d_in[3];
    const float* b1   = (const float*)d_in[4];
    const float* W2   = (const float*)d_in[5];
    const float* b2   = (const float*)d_in[6];
    const float* W3   = (const float*)d_in[7];
    const float* b3   = (const float*)d_in[8];
    const float* W4   = (const float*)d_in[9];
    const float* b4   = (const float*)d_in[10];
    const float* Wout = (const float*)d_in[11];
    const float* bout = (const float*)d_in[12];
    float* out = (float*)d_out;

    char* ws = (char*)d_ws;
    size_t off = 0;
    auto alloc = [&](size_t bytes) -> void* {
        off = (off + 255) & ~(size_t)255;
        void* p = ws + off;
        off += bytes;
        return p;
    };
    bf16* W0b = (bf16*)alloc((size_t)4096 * 4096 * 2);
    bf16* W1b = (bf16*)alloc((size_t)M_ * 64 * 32 * 2);
    bf16* W2b = (bf16*)alloc((size_t)M_ * 128 * 64 * 2);
    bf16* W3b = (bf16*)alloc((size_t)M_ * 256 * 128 * 2);
    bf16* W4b = (bf16*)alloc((size_t)M_ * 512 * 256 * 2);
    bf16* xb  = (bf16*)alloc((size_t)B_ * 4096 * 2);
    bf16* h0  = (bf16*)alloc((size_t)B_ * 4096 * 2);   // [B][128][32]

    CvtArgs ca;
    ca.src[0] = (const float4*)x;  ca.dst[0] = (short4*)xb;
    ca.src[1] = (const float4*)W0; ca.dst[1] = (short4*)W0b;
    ca.src[2] = (const float4*)W1; ca.dst[2] = (short4*)W1b;
    ca.src[3] = (const float4*)W2; ca.dst[3] = (short4*)W2b;
    ca.src[4] = (const float4*)W3; ca.dst[4] = (short4*)W3b;
    ca.src[5] = (const float4*)W4; ca.dst[5] = (short4*)W4b;
    cvt_all<<<(10813440 + 255) / 256, 256, 0, stream>>>(ca);

    {
        dim3 g(4096 / 64, B_ / 128, 1);
        gemm_l0<<<g, 256, 0, stream>>>(xb, W0b, b0, h0);
    }
    {
        dim3 g(B_ / 64, M_, 1);
        modules_fused<<<g, 256, 0, stream>>>(h0, W1b, b1, W2b, b2, W3b, b3,
                                             W4b, b4, Wout, bout, out);
    }
}